// Round 5
// baseline (1785.363 us; speedup 1.0000x reference)
//
#include <hip/hip_runtime.h>
#include <cstddef>
#include <float.h>

#define BB 32
#define KK 10
#define NN 128
#define FF 512
#define NITER 30
#define NCH 2              // column-chunk blocks per (b,k) tile
#define ROWS_PB 64         // rows per block
#define GROUP (KK * NCH)   // blocks per b-group = 20

constexpr float LRc  = 0.5f;
constexpr float RHOc = 10.0f;

// ---------------------------------------------------------------------------
// xn[row] = dot(X[row], X[row]); sequential fmaf chain matching distc's
// accumulation order bitwise so diag(dist) is exactly 0.
// ---------------------------------------------------------------------------
__global__ __launch_bounds__(128) void xn_kernel(const float* __restrict__ X,
                                                 float* __restrict__ xn) {
    int row = blockIdx.x * 128 + threadIdx.x;
    const float* xr = X + (size_t)row * FF;
    float acc = 0.f;
    for (int i = 0; i < FF; i += 4) {
        float4 v = *(const float4*)(xr + i);
        acc = fmaf(v.x, v.x, acc);
        acc = fmaf(v.y, v.y, acc);
        acc = fmaf(v.z, v.z, acc);
        acc = fmaf(v.w, v.w, acc);
    }
    xn[row] = acc;
}

// ---------------------------------------------------------------------------
// C[b,i,j] = relu(xn_i + xn_j - 2*dot(X_i, X_j)).  Grid (8, B), 16-row strips.
// ---------------------------------------------------------------------------
__global__ __launch_bounds__(256) void distc_kernel(const float* __restrict__ X,
                                                    const float* __restrict__ xn,
                                                    float* __restrict__ C) {
    const int b  = blockIdx.y;
    const int i0 = blockIdx.x * 16;
    const int tid = threadIdx.x;
    const int tx = tid & 31;
    const int ty = tid >> 5;

    __shared__ float Xi[16][65];
    __shared__ float Xj[NN][65];

    float acc[2][4];
#pragma unroll
    for (int a = 0; a < 2; ++a)
#pragma unroll
        for (int c = 0; c < 4; ++c) acc[a][c] = 0.f;

    const float* Xb = X + (size_t)b * NN * FF;

    for (int kk = 0; kk < FF; kk += 64) {
        {
            int r = tid >> 4, c4 = tid & 15;
            float4 v = *(const float4*)(Xb + (size_t)(i0 + r) * FF + kk + c4 * 4);
            Xi[r][c4 * 4 + 0] = v.x; Xi[r][c4 * 4 + 1] = v.y;
            Xi[r][c4 * 4 + 2] = v.z; Xi[r][c4 * 4 + 3] = v.w;
        }
        for (int t = tid; t < NN * 16; t += 256) {
            int r = t >> 4, c4 = t & 15;
            float4 v = *(const float4*)(Xb + (size_t)r * FF + kk + c4 * 4);
            Xj[r][c4 * 4 + 0] = v.x; Xj[r][c4 * 4 + 1] = v.y;
            Xj[r][c4 * 4 + 2] = v.z; Xj[r][c4 * 4 + 3] = v.w;
        }
        __syncthreads();
#pragma unroll 8
        for (int kidx = 0; kidx < 64; ++kidx) {
            float a0 = Xi[ty][kidx];
            float a1 = Xi[ty + 8][kidx];
            float bb[4];
#pragma unroll
            for (int ci = 0; ci < 4; ++ci) bb[ci] = Xj[tx + 32 * ci][kidx];
#pragma unroll
            for (int ci = 0; ci < 4; ++ci) {
                acc[0][ci] = fmaf(a0, bb[ci], acc[0][ci]);
                acc[1][ci] = fmaf(a1, bb[ci], acc[1][ci]);
            }
        }
        __syncthreads();
    }

#pragma unroll
    for (int ri = 0; ri < 2; ++ri) {
        int i = i0 + ty + 8 * ri;
        float xni = xn[b * NN + i];
#pragma unroll
        for (int ci = 0; ci < 4; ++ci) {
            int j = tx + 32 * ci;
            float d = (xni + xn[b * NN + j]) - 2.f * acc[ri][ci];
            C[((size_t)b * NN + i) * NN + j] = fmaxf(d, 0.f);
        }
    }
}

// ---------------------------------------------------------------------------
// Persistent solver, PLAIN launch (cooperative API rejected twice in this
// harness). Co-residency by construction: __launch_bounds__(256,3) => 3
// blocks/CU guaranteed (VGPR cap 170 >> ~90 used; LDS 37.4KB -> 4/CU), so
// capacity 768 >= grid 640; blocks never retire before their group barrier,
// so greedy dispatch places all 640 -> per-b spin barrier cannot starve.
// Spin carries a bounded guard: converts a placement failure into a wrong
// answer instead of a hang.
// S lives in registers (8 float4/thread) for all 30 steps; C tile in LDS.
// ---------------------------------------------------------------------------
__global__ __launch_bounds__(256, 3) void solve_kernel(
    const float* __restrict__ C, const float* __restrict__ Q,
    const float* __restrict__ theta,
    float* pA, float* pB, float* cA, float* cB,
    unsigned int* cnt, float* out) {
    const int blk = blockIdx.x;      // 0..639
    const int bk  = blk >> 1;        // 0..319
    const int ch  = blk & 1;         // 0..1
    const int b   = bk / KK;
    const int kown = bk - b * KK;
    const int tid = threadIdx.x;
    const int hw = tid >> 5;         // half-wave 0..7
    const int ln = tid & 31;

    __shared__ float Cs[ROWS_PB][NN];   // 32 KB
    __shared__ float wsh[NN];
    __shared__ float pacc[8][NN];
    __shared__ float cpart[8];
    __shared__ float Abuf;

    // ---- stage C tile (coalesced float4), load q, init S = 1/128
    const float* Cb = C + ((size_t)b * NN + ch * ROWS_PB) * NN;
    for (int i = tid; i < ROWS_PB * (NN / 4); i += 256) {
        int r = i >> 5, c4 = i & 31;
        *(float4*)&Cs[r][c4 * 4] = *(const float4*)(Cb + (size_t)r * NN + c4 * 4);
    }
    float4 sv[8];
    float qv[8];
#pragma unroll
    for (int it = 0; it < 8; ++it) {
        qv[it] = Q[bk * NN + ch * ROWS_PB + it * 8 + hw];
        sv[it].x = 0.0078125f; sv[it].y = 0.0078125f;
        sv[it].z = 0.0078125f; sv[it].w = 0.0078125f;
    }
    const float th = theta[bk];
    __syncthreads();

    float* pin = pA; float* pout = pB;
    float* cin = cA; float* cout = cB;

    for (int t = 0; t <= NITER; ++t) {
        float A = 0.f;
        if (t > 0) {
            // ---- w (min-over-k subgradient, ties split) and penalty coeff
            if (tid < NN) {
                float pv[KK];
                float pmin = FLT_MAX;
#pragma unroll
                for (int kq = 0; kq < KK; ++kq) {
                    const float* pp = pin + (size_t)(b * KK + kq) * NCH * NN + tid;
                    float v = 0.f;
#pragma unroll
                    for (int c2 = 0; c2 < NCH; ++c2)
                        v += __hip_atomic_load(pp + c2 * NN, __ATOMIC_RELAXED,
                                               __HIP_MEMORY_SCOPE_AGENT);
                    pv[kq] = v;
                    pmin = fminf(pmin, v);
                }
                int nmin = 0;
                float mine = 0.f;
#pragma unroll
                for (int kq = 0; kq < KK; ++kq) {
                    nmin += (pv[kq] == pmin) ? 1 : 0;
                    if (kq == kown) mine = pv[kq];
                }
                wsh[tid] = (mine == pmin) ? (1.0f / (float)nmin) : 0.0f;
            }
            if (tid == 0) {
                float cost = 0.f;
#pragma unroll
                for (int c2 = 0; c2 < NCH; ++c2)
                    cost += __hip_atomic_load(cin + bk * NCH + c2,
                                              __ATOMIC_RELAXED,
                                              __HIP_MEMORY_SCOPE_AGENT);
                float pen = fmaxf(cost - th, 0.0f);
                Abuf = 2.0f * RHOc * pen;
            }
            __syncthreads();
            A = Abuf;
        }

        float4 pl = {0.f, 0.f, 0.f, 0.f};
        float cl = 0.f;

#pragma unroll
        for (int it = 0; it < 8; ++it) {
            const int row = it * 8 + hw;
            float4 c = *(const float4*)&Cs[row][ln * 4];
            float4 s = sv[it];
            const float ql = qv[it];

            if (t > 0) {
                float4 w4 = *(const float4*)&wsh[ln * 4];
                float4 g;
                g.x = fmaf(-A, c.x, w4.x);
                g.y = fmaf(-A, c.y, w4.y);
                g.z = fmaf(-A, c.z, w4.z);
                g.w = fmaf(-A, c.w, w4.w);

                float rd = (s.x * g.x + s.y * g.y) + (s.z * g.z + s.w * g.w);
#pragma unroll
                for (int off = 16; off; off >>= 1) rd += __shfl_xor(rd, off, 32);

                const float lq = LRc * ql;
                float4 tt;
                tt.x = __logf(s.x) + lq * s.x * (g.x - rd);
                tt.y = __logf(s.y) + lq * s.y * (g.y - rd);
                tt.z = __logf(s.z) + lq * s.z * (g.z - rd);
                tt.w = __logf(s.w) + lq * s.w * (g.w - rd);

                float m = fmaxf(fmaxf(tt.x, tt.y), fmaxf(tt.z, tt.w));
#pragma unroll
                for (int off = 16; off; off >>= 1) m = fmaxf(m, __shfl_xor(m, off, 32));

                float4 u;
                u.x = __expf(tt.x - m); u.y = __expf(tt.y - m);
                u.z = __expf(tt.z - m); u.w = __expf(tt.w - m);
                float ss = (u.x + u.y) + (u.z + u.w);
#pragma unroll
                for (int off = 16; off; off >>= 1) ss += __shfl_xor(ss, off, 32);
                float inv = 1.0f / ss;
                s.x = u.x * inv; s.y = u.y * inv;
                s.z = u.z * inv; s.w = u.w * inv;
                sv[it] = s;
            }

            pl.x += ql * s.x; pl.y += ql * s.y;
            pl.z += ql * s.z; pl.w += ql * s.w;
            cl += ql * ((s.x * c.x + s.y * c.y) + (s.z * c.z + s.w * c.w));
        }

        *(float4*)&pacc[hw][ln * 4] = pl;
#pragma unroll
        for (int off = 16; off; off >>= 1) cl += __shfl_xor(cl, off, 32);
        if (ln == 0) cpart[hw] = cl;
        __syncthreads();

        if (tid < NN) {
            float p = 0.f;
#pragma unroll
            for (int h2 = 0; h2 < 8; ++h2) p += pacc[h2][tid];
            __hip_atomic_store(pout + ((size_t)bk * NCH + ch) * NN + tid, p,
                               __ATOMIC_RELAXED, __HIP_MEMORY_SCOPE_AGENT);
        }
        if (tid == 0) {
            float cc = 0.f;
#pragma unroll
            for (int h2 = 0; h2 < 8; ++h2) cc += cpart[h2];
            __hip_atomic_store(cout + bk * NCH + ch, cc,
                               __ATOMIC_RELAXED, __HIP_MEMORY_SCOPE_AGENT);
        }
        __syncthreads();   // block's partial stores all issued

        // ---- per-b barrier: leader releases, spins to GROUP*(t+1), acquires
        if (tid == 0) {
            __hip_atomic_fetch_add(&cnt[b], 1u, __ATOMIC_RELEASE,
                                   __HIP_MEMORY_SCOPE_AGENT);
            const unsigned target = (unsigned)(GROUP * (t + 1));
            long guard = 0;
            while (__hip_atomic_load(&cnt[b], __ATOMIC_RELAXED,
                                     __HIP_MEMORY_SCOPE_AGENT) < target) {
                __builtin_amdgcn_s_sleep(2);
                if (++guard > 5000000L) break;   // anti-hang insurance
            }
            (void)__hip_atomic_load(&cnt[b], __ATOMIC_ACQUIRE,
                                    __HIP_MEMORY_SCOPE_AGENT);
        }
        __syncthreads();

        float* tp = pin; pin = pout; pout = tp;
        float* tc = cin; cin = cout; cout = tc;
    }

    // ---- final output: p[b,k,j] = sum of the NCH chunk partials (iter 30)
    if (ch == 0 && tid < NN) {
        float v = 0.f;
#pragma unroll
        for (int c2 = 0; c2 < NCH; ++c2)
            v += __hip_atomic_load(pin + ((size_t)bk * NCH + c2) * NN + tid,
                                   __ATOMIC_RELAXED, __HIP_MEMORY_SCOPE_AGENT);
        out[bk * NN + tid] = v;
    }
}

extern "C" void kernel_launch(void* const* d_in, const int* in_sizes, int n_in,
                              void* d_out, int out_size, void* d_ws, size_t ws_size,
                              hipStream_t stream) {
    const float* X     = (const float*)d_in[0];   // [B, N, F]
    const float* Q     = (const float*)d_in[1];   // [B, K, N]
    const float* theta = (const float*)d_in[2];   // [B, K]

    float* ws  = (float*)d_ws;
    float* Cw  = ws;                                    // B*N*N      = 524288
    float* xnw = Cw + (size_t)BB * NN * NN;             // B*N        = 4096
    float* pA  = xnw + BB * NN;                         // B*K*NCH*N  = 81920
    float* pB  = pA + (size_t)BB * KK * NCH * NN;       // 81920
    float* cA  = pB + (size_t)BB * KK * NCH * NN;       // B*K*NCH    = 640
    float* cB  = cA + BB * KK * NCH;                    // 640
    unsigned int* cnt = (unsigned int*)(cB + BB * KK * NCH);  // 32 counters

    hipMemsetAsync(cnt, 0, BB * sizeof(unsigned int), stream);
    xn_kernel<<<BB, 128, 0, stream>>>(X, xnw);
    distc_kernel<<<dim3(8, BB), 256, 0, stream>>>(X, xnw, Cw);

    solve_kernel<<<BB * KK * NCH, 256, 0, stream>>>(
        Cw, Q, theta, pA, pB, cA, cB, cnt, (float*)d_out);
}

// Round 6
// 432.158 us; speedup vs baseline: 4.1313x; 4.1313x over previous
//
#include <hip/hip_runtime.h>
#include <cstddef>
#include <float.h>

#define BB 32
#define KK 10
#define NN 128
#define FF 512
#define NITER 30
#define NCH 4          // row chunks per (b,k) tile
#define NROWCH 32      // rows per chunk

constexpr float LRc  = 0.5f;
constexpr float RHOc = 10.0f;

typedef _Float16 half4 __attribute__((ext_vector_type(4)));

// ---------------------------------------------------------------------------
// xn[row] = dot(X[row], X[row]); sequential fmaf chain matching distc's
// accumulation order bitwise so diag(dist) is exactly 0.
// ---------------------------------------------------------------------------
__global__ __launch_bounds__(128) void xn_kernel(const float* __restrict__ X,
                                                 float* __restrict__ xn) {
    int row = blockIdx.x * 128 + threadIdx.x;
    const float* xr = X + (size_t)row * FF;
    float acc = 0.f;
    for (int i = 0; i < FF; i += 4) {
        float4 v = *(const float4*)(xr + i);
        acc = fmaf(v.x, v.x, acc);
        acc = fmaf(v.y, v.y, acc);
        acc = fmaf(v.z, v.z, acc);
        acc = fmaf(v.w, v.w, acc);
    }
    xn[row] = acc;
}

// ---------------------------------------------------------------------------
// C[b,i,j] = relu(xn_i + xn_j - 2*dot(X_i, X_j)).  Grid (8, B), 16-row strips.
// Inner loop: 4-k register blocking with ds_read_b128 (stride 68 floats =
// 272 B: 16B-aligned and bank-balanced). k-chain order stays strictly
// sequential (0..511) to keep diag exactly 0 vs xn_kernel.
// ---------------------------------------------------------------------------
__global__ __launch_bounds__(256) void distc_kernel(const float* __restrict__ X,
                                                    const float* __restrict__ xn,
                                                    float* __restrict__ C) {
    const int b  = blockIdx.y;
    const int i0 = blockIdx.x * 16;
    const int tid = threadIdx.x;
    const int tx = tid & 31;
    const int ty = tid >> 5;

    __shared__ float Xi[16][68];
    __shared__ float Xj[NN][68];

    float acc[2][4];
#pragma unroll
    for (int a = 0; a < 2; ++a)
#pragma unroll
        for (int c = 0; c < 4; ++c) acc[a][c] = 0.f;

    const float* Xb = X + (size_t)b * NN * FF;

    for (int kk = 0; kk < FF; kk += 64) {
        {
            int r = tid >> 4, c4 = tid & 15;
            float4 v = *(const float4*)(Xb + (size_t)(i0 + r) * FF + kk + c4 * 4);
            *(float4*)&Xi[r][c4 * 4] = v;
        }
        for (int t = tid; t < NN * 16; t += 256) {
            int r = t >> 4, c4 = t & 15;
            float4 v = *(const float4*)(Xb + (size_t)r * FF + kk + c4 * 4);
            *(float4*)&Xj[r][c4 * 4] = v;
        }
        __syncthreads();
#pragma unroll
        for (int k4 = 0; k4 < 16; ++k4) {
            float4 a0 = *(const float4*)&Xi[ty][k4 * 4];
            float4 a1 = *(const float4*)&Xi[ty + 8][k4 * 4];
            float4 b0 = *(const float4*)&Xj[tx][k4 * 4];
            float4 b1 = *(const float4*)&Xj[tx + 32][k4 * 4];
            float4 b2 = *(const float4*)&Xj[tx + 64][k4 * 4];
            float4 b3 = *(const float4*)&Xj[tx + 96][k4 * 4];
            const float ar[2][4] = {{a0.x, a0.y, a0.z, a0.w},
                                    {a1.x, a1.y, a1.z, a1.w}};
            const float br[4][4] = {{b0.x, b0.y, b0.z, b0.w},
                                    {b1.x, b1.y, b1.z, b1.w},
                                    {b2.x, b2.y, b2.z, b2.w},
                                    {b3.x, b3.y, b3.z, b3.w}};
#pragma unroll
            for (int ri = 0; ri < 2; ++ri)
#pragma unroll
                for (int ci = 0; ci < 4; ++ci)
#pragma unroll
                    for (int kq = 0; kq < 4; ++kq)   // k-sequential chain
                        acc[ri][ci] = fmaf(ar[ri][kq], br[ci][kq], acc[ri][ci]);
        }
        __syncthreads();
    }

#pragma unroll
    for (int ri = 0; ri < 2; ++ri) {
        int i = i0 + ty + 8 * ri;
        float xni = xn[b * NN + i];
#pragma unroll
        for (int ci = 0; ci < 4; ++ci) {
            int j = tx + 32 * ci;
            float d = (xni + xn[b * NN + j]) - 2.f * acc[ri][ci];
            C[((size_t)b * NN + i) * NN + j] = fmaxf(d, 0.f);
        }
    }
}

// ---------------------------------------------------------------------------
__global__ __launch_bounds__(128) void rowsum_kernel(const float* __restrict__ C,
                                                     float* __restrict__ rs) {
    int b = blockIdx.x, i = threadIdx.x;
    const float* row = C + ((size_t)b * NN + i) * NN;
    float acc = 0.f;
#pragma unroll 8
    for (int j = 0; j < NN; j += 4) {
        float4 v = *(const float4*)(row + j);
        acc += (v.x + v.y) + (v.z + v.w);
    }
    rs[b * NN + i] = acc;
}

// ---------------------------------------------------------------------------
// S = 1/128 everywhere, fp16 (0x2000 = 2^-7 exact). 655360 uint4 = 10.5 MB.
// ---------------------------------------------------------------------------
__global__ __launch_bounds__(256) void sfill_kernel(uint4* __restrict__ S) {
    size_t t = (size_t)blockIdx.x * 256 + threadIdx.x;
    S[t] = make_uint4(0x20002000u, 0x20002000u, 0x20002000u, 0x20002000u);
}

// ---------------------------------------------------------------------------
// p0/cost0 analytic from uniform S (validated bitwise in round 2).
// ---------------------------------------------------------------------------
__global__ __launch_bounds__(64) void init_kernel(const float* __restrict__ Q,
                                                  const float* __restrict__ rs,
                                                  float* __restrict__ pPart,
                                                  float* __restrict__ cPart) {
    int bk = blockIdx.x;
    int b = bk / KK;
    int ln = threadIdx.x;
    float q0 = Q[bk * NN + ln], q1 = Q[bk * NN + 64 + ln];
    float r0 = rs[b * NN + ln], r1 = rs[b * NN + 64 + ln];
    float sq  = q0 + q1;
    float sqr = q0 * r0 + q1 * r1;
#pragma unroll
    for (int off = 32; off; off >>= 1) {
        sq  += __shfl_xor(sq,  off, 64);
        sqr += __shfl_xor(sqr, off, 64);
    }
    float p0 = sq * 0.0078125f;
    float c0 = sqr * 0.0078125f;
    float* pp = pPart + (size_t)bk * NCH * NN;
    pp[ln] = p0; pp[64 + ln] = p0;
#pragma unroll
    for (int c2 = 1; c2 < NCH; ++c2) {
        pp[c2 * NN + ln] = 0.f;
        pp[c2 * NN + 64 + ln] = 0.f;
    }
    if (ln == 0) {
        cPart[bk * NCH + 0] = c0;
        cPart[bk * NCH + 1] = 0.f;
        cPart[bk * NCH + 2] = 0.f;
        cPart[bk * NCH + 3] = 0.f;
    }
}

// ---------------------------------------------------------------------------
// One mirror-ascent step; S state in fp16 (self-renormalizing through the
// ln->softmax round-trip). Grid (B*K, NCH), block 256 = 8 half-waves; each
// half-wave owns one 128-wide row (32 lanes x 4 cols).
// ---------------------------------------------------------------------------
__global__ __launch_bounds__(256) void step_kernel(
    _Float16* __restrict__ S, const float* __restrict__ C,
    const float* __restrict__ Q, const float* __restrict__ pPart_in,
    const float* __restrict__ cPart_in, const float* __restrict__ theta,
    float* __restrict__ pPart_out, float* __restrict__ cPart_out) {
    const int bk = blockIdx.x;       // 0..319
    const int ch = blockIdx.y;       // 0..3
    const int b  = bk / KK;
    const int kown = bk - b * KK;
    const int tid = threadIdx.x;
    const int hw = tid >> 5;
    const int ln = tid & 31;

    __shared__ float wsh[NN];
    __shared__ float Qs[NROWCH];
    __shared__ float pacc[8][NN];
    __shared__ float cpart[8];
    __shared__ float Abuf;

    // issue row loads up front; they drain together with the w-partial loads
    half4 svh[4];
    float4 cv[4];
#pragma unroll
    for (int it = 0; it < 4; ++it) {
        int l = ch * NROWCH + it * 8 + hw;
        svh[it] = *(const half4*)(S + ((size_t)bk * NN + l) * NN + ln * 4);
        cv[it] = *(const float4*)(C + ((size_t)b * NN + l) * NN + ln * 4);
    }

    if (tid < NROWCH) Qs[tid] = Q[bk * NN + ch * NROWCH + tid];

    if (tid < NN) {
        float pv[KK];
        float pmin = FLT_MAX;
#pragma unroll
        for (int kq = 0; kq < KK; ++kq) {
            const float* pp = pPart_in + (size_t)(b * KK + kq) * NCH * NN + tid;
            float v = 0.f;
#pragma unroll
            for (int c2 = 0; c2 < NCH; ++c2) v += pp[c2 * NN];
            pv[kq] = v;
            pmin = fminf(pmin, v);
        }
        int cnt = 0;
        float mine = 0.f;
#pragma unroll
        for (int kq = 0; kq < KK; ++kq) {
            cnt += (pv[kq] == pmin) ? 1 : 0;
            if (kq == kown) mine = pv[kq];
        }
        wsh[tid] = (mine == pmin) ? (1.0f / (float)cnt) : 0.0f;
    }
    if (tid == 0) {
        float cost = 0.f;
#pragma unroll
        for (int c2 = 0; c2 < NCH; ++c2) cost += cPart_in[bk * NCH + c2];
        float pen = fmaxf(cost - theta[bk], 0.0f);
        Abuf = 2.0f * RHOc * pen;
    }
    __syncthreads();
    const float A = Abuf;

    float4 pl = {0.f, 0.f, 0.f, 0.f};
    float cl = 0.f;

#pragma unroll
    for (int it = 0; it < 4; ++it) {
        const int lrow = it * 8 + hw;
        float4 s;
        s.x = (float)svh[it].x; s.y = (float)svh[it].y;
        s.z = (float)svh[it].z; s.w = (float)svh[it].w;
        float4 c = cv[it];
        float4 w4 = *(const float4*)&wsh[ln * 4];

        float4 g;
        g.x = fmaf(-A, c.x, w4.x);
        g.y = fmaf(-A, c.y, w4.y);
        g.z = fmaf(-A, c.z, w4.z);
        g.w = fmaf(-A, c.w, w4.w);

        float rd = (s.x * g.x + s.y * g.y) + (s.z * g.z + s.w * g.w);
#pragma unroll
        for (int off = 16; off; off >>= 1) rd += __shfl_xor(rd, off, 32);

        const float lq = LRc * Qs[lrow];
        float4 t;
        t.x = __logf(s.x) + lq * s.x * (g.x - rd);
        t.y = __logf(s.y) + lq * s.y * (g.y - rd);
        t.z = __logf(s.z) + lq * s.z * (g.z - rd);
        t.w = __logf(s.w) + lq * s.w * (g.w - rd);

        float m = fmaxf(fmaxf(t.x, t.y), fmaxf(t.z, t.w));
#pragma unroll
        for (int off = 16; off; off >>= 1) m = fmaxf(m, __shfl_xor(m, off, 32));

        float4 u;
        u.x = __expf(t.x - m); u.y = __expf(t.y - m);
        u.z = __expf(t.z - m); u.w = __expf(t.w - m);
        float ss = (u.x + u.y) + (u.z + u.w);
#pragma unroll
        for (int off = 16; off; off >>= 1) ss += __shfl_xor(ss, off, 32);
        float inv = 1.0f / ss;
        s.x = u.x * inv; s.y = u.y * inv; s.z = u.z * inv; s.w = u.w * inv;

        half4 oh;
        oh.x = (_Float16)s.x; oh.y = (_Float16)s.y;
        oh.z = (_Float16)s.z; oh.w = (_Float16)s.w;
        *(half4*)(S + ((size_t)bk * NN + ch * NROWCH + lrow) * NN + ln * 4) = oh;

        const float ql = Qs[lrow];
        pl.x += ql * s.x; pl.y += ql * s.y;
        pl.z += ql * s.z; pl.w += ql * s.w;
        cl += ql * ((s.x * c.x + s.y * c.y) + (s.z * c.z + s.w * c.w));
    }

    *(float4*)&pacc[hw][ln * 4] = pl;
#pragma unroll
    for (int off = 16; off; off >>= 1) cl += __shfl_xor(cl, off, 32);
    if (ln == 0) cpart[hw] = cl;
    __syncthreads();

    if (tid < NN) {
        float p = 0.f;
#pragma unroll
        for (int h2 = 0; h2 < 8; ++h2) p += pacc[h2][tid];
        pPart_out[((size_t)bk * NCH + ch) * NN + tid] = p;
    }
    if (tid == 0) {
        float cc = 0.f;
#pragma unroll
        for (int h2 = 0; h2 < 8; ++h2) cc += cpart[h2];
        cPart_out[bk * NCH + ch] = cc;
    }
}

// ---------------------------------------------------------------------------
__global__ __launch_bounds__(128) void finalize_kernel(
    const float* __restrict__ pPart, float* __restrict__ out) {
    int bk = blockIdx.x;
    int j = threadIdx.x;
    float v = 0.f;
#pragma unroll
    for (int c2 = 0; c2 < NCH; ++c2) v += pPart[((size_t)bk * NCH + c2) * NN + j];
    out[bk * NN + j] = v;
}

extern "C" void kernel_launch(void* const* d_in, const int* in_sizes, int n_in,
                              void* d_out, int out_size, void* d_ws, size_t ws_size,
                              hipStream_t stream) {
    const float* X     = (const float*)d_in[0];   // [B, N, F]
    const float* Q     = (const float*)d_in[1];   // [B, K, N]
    const float* theta = (const float*)d_in[2];   // [B, K]

    float* ws  = (float*)d_ws;
    float* Cw  = ws;                                    // B*N*N      = 524288 f32
    float* xnw = Cw + (size_t)BB * NN * NN;             // B*N        = 4096
    float* rsw = xnw + BB * NN;                         // B*N        = 4096
    float* pA  = rsw + BB * NN;                         // B*K*NCH*N  = 163840
    float* pB  = pA + (size_t)BB * KK * NCH * NN;       // 163840
    float* cA  = pB + (size_t)BB * KK * NCH * NN;       // B*K*NCH    = 1280
    float* cB  = cA + BB * KK * NCH;                    // 1280
    _Float16* Sh = (_Float16*)(cB + BB * KK * NCH);     // B*K*N*N halves = 10.5 MB

    sfill_kernel<<<2560, 256, 0, stream>>>((uint4*)Sh);
    xn_kernel<<<BB, 128, 0, stream>>>(X, xnw);
    distc_kernel<<<dim3(8, BB), 256, 0, stream>>>(X, xnw, Cw);
    rowsum_kernel<<<BB, 128, 0, stream>>>(Cw, rsw);
    init_kernel<<<BB * KK, 64, 0, stream>>>(Q, rsw, pA, cA);

    float* pin = pA; float* cin = cA;
    float* pout = pB; float* cout = cB;
    for (int t = 1; t <= NITER; ++t) {
        step_kernel<<<dim3(BB * KK, NCH), 256, 0, stream>>>(
            Sh, Cw, Q, pin, cin, theta, pout, cout);
        float* tp = pin; pin = pout; pout = tp;
        float* tc = cin; cin = cout; cout = tc;
    }
    finalize_kernel<<<BB * KK, 128, 0, stream>>>(pin, (float*)d_out);
}